// Round 3
// baseline (31.166 us; speedup 1.0000x reference)
//
#include <hip/hip_runtime.h>

#define EPSF 1e-4f

// Fast per-2x2-block computation (see R1 notes): v_rcp_f32 for shared
// divisors, native v_exp_f32, FMA contraction allowed, reference summation
// order preserved. absmax 0.0078 vs threshold 0.058.
__device__ __forceinline__ float fuzzy_one(float v0, float v1, float v2, float v3) {
    float k0 = (v1 + v2) * 0.5f;
    float k1 = (((v0 + v1) + v2) + v3) * 0.25f;
    float vavg = (k0 + k1) * 0.5f;

    float o0 = fabsf(v0 - vavg);
    float o1 = fabsf(v1 - vavg);
    float o2 = fabsf(v2 - vavg);
    float o3 = fabsf(v3 - vavg);
    float sg0 = (o1 + o2) * 0.5f + EPSF;
    float sg1 = (((o0 + o1) + o2) + o3) * 0.25f + EPSF;

    float rs0 = __builtin_amdgcn_rcpf(sg0);
    float rs1 = __builtin_amdgcn_rcpf(sg1);
    float c0 = -0.5f * rs0 * rs0;
    float c1 = -0.5f * rs1 * rs1;

    float dv00 = v0 - k0, dv01 = v1 - k0, dv02 = v2 - k0, dv03 = v3 - k0;
    float dv10 = v0 - k1, dv11 = v1 - k1, dv12 = v2 - k1, dv13 = v3 - k1;

    float p00 = __expf(dv00 * dv00 * c0);
    float p01 = __expf(dv01 * dv01 * c0);
    float p02 = __expf(dv02 * dv02 * c0);
    float p03 = __expf(dv03 * dv03 * c0);
    float p10 = __expf(dv10 * dv10 * c1);
    float p11 = __expf(dv11 * dv11 * c1);
    float p12 = __expf(dv12 * dv12 * c1);
    float p13 = __expf(dv13 * dv13 * c1);

    float a0 = (p00 + p10) * 0.5f;
    float a1 = (p01 + p11) * 0.5f;
    float a2 = (p02 + p12) * 0.5f;
    float a3 = (p03 + p13) * 0.5f;
    float pm0 = fmaxf(p00, p10);
    float pm1 = fmaxf(p01, p11);
    float pm2 = fmaxf(p02, p12);
    float pm3 = fmaxf(p03, p13);
    float thresh = fminf(fminf(fminf(pm0, pm1), pm2), pm3);

    bool primary = (a1 >= thresh);
    bool s_cond  = (sg1 < 0.001f);

    float num = ((a0 * v0 + a1 * v1) + a2 * v2) + a3 * v3;
    float den = ((a0 + a1) + a2) + a3;
    float denoised = num * __builtin_amdgcn_rcpf(den);

    return primary ? k1 : (s_cond ? vavg : denoised);
}

// x: (512, 256, 256) f32 flat; out: (512, 128, 128) f32.
// Each thread: 2x8 input patch (4x global_load_dwordx4 in flight) -> 4
// outputs via one global_store_dwordx4. 2.1M threads, 8192 blocks.
__global__ void __launch_bounds__(256) fuzzy_kernel(const float* __restrict__ x,
                                                    float* __restrict__ out) {
    unsigned t = blockIdx.x * 256u + threadIdx.x;     // 0 .. 2097151
    unsigned jp = t & 31u;                             // 8-col group within row (32 per row)
    unsigned i  = (t >> 5) & 127u;                     // output row
    unsigned bc = t >> 12;                             // channel (512)

    const float4* top = reinterpret_cast<const float4*>(
        x + (size_t)bc * 65536u + (size_t)(2u * i) * 256u) + 2u * jp;
    const float4* bot = top + 64;                      // next input row (256 floats)
    float4 a0 = top[0];
    float4 a1 = top[1];
    float4 b0 = bot[0];
    float4 b1 = bot[1];

    float4 r;
    r.x = fuzzy_one(a0.x, a0.y, b0.x, b0.y);
    r.y = fuzzy_one(a0.z, a0.w, b0.z, b0.w);
    r.z = fuzzy_one(a1.x, a1.y, b1.x, b1.y);
    r.w = fuzzy_one(a1.z, a1.w, b1.z, b1.w);

    float4* o = reinterpret_cast<float4*>(
        out + (size_t)bc * 16384u + (size_t)i * 128u) + jp;
    *o = r;
}

extern "C" void kernel_launch(void* const* d_in, const int* in_sizes, int n_in,
                              void* d_out, int out_size, void* d_ws, size_t ws_size,
                              hipStream_t stream) {
    const float* x = (const float*)d_in[0];
    float* out = (float*)d_out;
    dim3 grid(8192), block(256);
    hipLaunchKernelGGL(fuzzy_kernel, grid, block, 0, stream, x, out);
}

// Round 4
// 31.010 us; speedup vs baseline: 1.0050x; 1.0050x over previous
//
#include <hip/hip_runtime.h>

#define EPSF 1e-4f

// Fast per-2x2-block computation (see R1 notes): v_rcp_f32 for shared
// divisors, native v_exp_f32, FMA contraction allowed, reference summation
// order preserved. absmax 0.0078 vs threshold 0.058.
__device__ __forceinline__ float fuzzy_one(float v0, float v1, float v2, float v3) {
    float k0 = (v1 + v2) * 0.5f;
    float k1 = (((v0 + v1) + v2) + v3) * 0.25f;
    float vavg = (k0 + k1) * 0.5f;

    float o0 = fabsf(v0 - vavg);
    float o1 = fabsf(v1 - vavg);
    float o2 = fabsf(v2 - vavg);
    float o3 = fabsf(v3 - vavg);
    float sg0 = (o1 + o2) * 0.5f + EPSF;
    float sg1 = (((o0 + o1) + o2) + o3) * 0.25f + EPSF;

    float rs0 = __builtin_amdgcn_rcpf(sg0);
    float rs1 = __builtin_amdgcn_rcpf(sg1);
    float c0 = -0.5f * rs0 * rs0;
    float c1 = -0.5f * rs1 * rs1;

    float dv00 = v0 - k0, dv01 = v1 - k0, dv02 = v2 - k0, dv03 = v3 - k0;
    float dv10 = v0 - k1, dv11 = v1 - k1, dv12 = v2 - k1, dv13 = v3 - k1;

    float p00 = __expf(dv00 * dv00 * c0);
    float p01 = __expf(dv01 * dv01 * c0);
    float p02 = __expf(dv02 * dv02 * c0);
    float p03 = __expf(dv03 * dv03 * c0);
    float p10 = __expf(dv10 * dv10 * c1);
    float p11 = __expf(dv11 * dv11 * c1);
    float p12 = __expf(dv12 * dv12 * c1);
    float p13 = __expf(dv13 * dv13 * c1);

    float a0 = (p00 + p10) * 0.5f;
    float a1 = (p01 + p11) * 0.5f;
    float a2 = (p02 + p12) * 0.5f;
    float a3 = (p03 + p13) * 0.5f;
    float pm0 = fmaxf(p00, p10);
    float pm1 = fmaxf(p01, p11);
    float pm2 = fmaxf(p02, p12);
    float pm3 = fmaxf(p03, p13);
    float thresh = fminf(fminf(fminf(pm0, pm1), pm2), pm3);

    bool primary = (a1 >= thresh);
    bool s_cond  = (sg1 < 0.001f);

    float num = ((a0 * v0 + a1 * v1) + a2 * v2) + a3 * v3;
    float den = ((a0 + a1) + a2) + a3;
    float denoised = num * __builtin_amdgcn_rcpf(den);

    return primary ? k1 : (s_cond ? vavg : denoised);
}

// x: (512, 256, 256) f32 flat; out: (512, 128, 128) f32.
// Each thread: TWO row-pairs (output rows i and i+64 of one channel).
// All 4 global_load_dwordx4 are lane-contiguous (1KB/wave/instr) — R2 showed
// lane-stride-2 loads regress; this keeps contiguity while doubling MLP.
__global__ void __launch_bounds__(256) fuzzy_kernel(const float* __restrict__ x,
                                                    float* __restrict__ out) {
    unsigned t = blockIdx.x * 256u + threadIdx.x;     // 0 .. 2097151
    unsigned jp = t & 63u;                             // float4 index within row
    unsigned i  = (t >> 6) & 63u;                      // output row (0..63)
    unsigned bc = t >> 12;                             // channel (512)

    const float4* topA = reinterpret_cast<const float4*>(
        x + (size_t)bc * 65536u + (size_t)(2u * i) * 256u) + jp;
    const float4* botA = topA + 64;       // input row 2i+1
    const float4* topB = topA + 8192;     // input row 2(i+64)
    const float4* botB = topB + 64;       // input row 2(i+64)+1
    float4 a0 = *topA;
    float4 b0 = *botA;
    float4 a1 = *topB;
    float4 b1 = *botB;

    float2 rA, rB;
    rA.x = fuzzy_one(a0.x, a0.y, b0.x, b0.y);
    rA.y = fuzzy_one(a0.z, a0.w, b0.z, b0.w);
    rB.x = fuzzy_one(a1.x, a1.y, b1.x, b1.y);
    rB.y = fuzzy_one(a1.z, a1.w, b1.z, b1.w);

    float2* oA = reinterpret_cast<float2*>(
        out + (size_t)bc * 16384u + (size_t)i * 128u) + jp;
    float2* oB = oA + 4096;               // output row i+64
    *oA = rA;
    *oB = rB;
}

extern "C" void kernel_launch(void* const* d_in, const int* in_sizes, int n_in,
                              void* d_out, int out_size, void* d_ws, size_t ws_size,
                              hipStream_t stream) {
    const float* x = (const float*)d_in[0];
    float* out = (float*)d_out;
    dim3 grid(8192), block(256);
    hipLaunchKernelGGL(fuzzy_kernel, grid, block, 0, stream, x, out);
}